// Round 2
// baseline (120.125 us; speedup 1.0000x reference)
//
#include <hip/hip_runtime.h>

// NonLinearConv2d: unfold(3x3,pad1) -> sum_k f((v_k - theta_kc)/D) with
// f(a) = softplus(a)^2 - softplus(a-DLT)^2, scaled, then BatchNorm2d
// (training, biased stats) per channel.
//
// Round 2: replace per-term exp/log (4 trans/term, branchy schedule) with a
// branchless 1024-entry LDS lookup table + lerp over a in [-8,24], exact
// linear tail f = DLT*(2a-DLT) for a > 24 via fma+cndmask. ~10 VALU + 1
// ds_read_b64 per term, single basic block.

constexpr float INV_D     = 13.333333333333334f;  // 1/(2*n*VT) = 1/0.075
constexpr float DLT       = 1.3333333333333333f;  // V_D/DENOM
constexpr float OUT_SCALE = 5.625e-5f;            // ALPHA * R_TIA
constexpr int   NCHUNK    = 512;                  // 32768 pixels / 64

constexpr int   NTAB      = 1024;                 // table segments
constexpr float TAB_SCALE = 32.0f;                // segments per unit of a
constexpr float TAB_LO    = -8.0f;                // table covers a in [-8, 24]
constexpr float XSCALE    = INV_D * TAB_SCALE;    // x -> t units (426.667)
constexpr float T_OFF     = -TAB_LO * TAB_SCALE;  // 256: t = a*32 + 256
// linear tail in t-units: f = 2*DLT*a - DLT^2, a = t/32 - 8
constexpr float LIN_A     = 2.0f * DLT / TAB_SCALE;          // 0.0833333
constexpr float LIN_B     = -(16.0f * DLT + DLT * DLT);      // -23.111111

__device__ inline float spf(float v) {
    // stable softplus, precise libm forms (one-time table build only)
    return fmaxf(v, 0.f) + log1pf(expf(-fabsf(v)));
}

// ---------------------------------------------------------------------------
// Kernel 1: V_out (into d_out) + per-(chunk,channel) partial sum / sumsq.
// Grid: 2048 blocks = 512 pixel-chunks x 4 channel-groups. Block: 256 = 4
// waves; each wave: 64 consecutive pixels x 4 channels.
// ---------------------------------------------------------------------------
__global__ __launch_bounds__(256)
void nlc_compute(const float* __restrict__ x, const float* __restrict__ theta,
                 float* __restrict__ vout, float* __restrict__ psum,
                 float* __restrict__ psq)
{
    __shared__ float2 tab[NTAB];
    __shared__ float  fs[NTAB + 1];
    __shared__ alignas(16) float thc[27 * 16];

    const int tid   = threadIdx.x;
    const int chunk = blockIdx.x >> 2;
    const int cbase = (blockIdx.x & 3) * 16;

    // --- build f-table (in a-units) + staged theta (in t-units) ---
    for (int j = tid; j < NTAB + 1; j += 256) {
        const float a  = TAB_LO + (float)j * (1.0f / TAB_SCALE);
        const float s1 = spf(a);
        const float s2 = spf(a - DLT);
        fs[j] = s1 * s1 - s2 * s2;
    }
    for (int i = tid; i < 27 * 16; i += 256) {
        const int k = i >> 4, cc = i & 15;
        thc[i] = T_OFF - theta[k * 64 + cbase + cc] * XSCALE;
    }
    __syncthreads();
    for (int i = tid; i < NTAB; i += 256)
        tab[i] = make_float2(fs[i], fs[i + 1] - fs[i]);
    __syncthreads();

    const int lane = tid & 63;
    const int wv   = tid >> 6;
    const int p    = chunk * 64 + lane;   // global pixel id
    const int n    = p >> 10;
    const int hw   = p & 1023;
    const int h    = hw >> 5;
    const int w    = hw & 31;

    // 27 patch values in t-units (channel-major then ki,kj = unfold order)
    float v[27];
    const float* xn = x + n * 3072;
#pragma unroll
    for (int ci = 0; ci < 3; ++ci) {
#pragma unroll
        for (int ki = 0; ki < 3; ++ki) {
#pragma unroll
            for (int kj = 0; kj < 3; ++kj) {
                const int hh = h + ki - 1;
                const int ww = w + kj - 1;
                float val = 0.f;
                if (hh >= 0 && hh < 32 && ww >= 0 && ww < 32)
                    val = xn[ci * 1024 + hh * 32 + ww];
                v[ci * 9 + ki * 3 + kj] = val * XSCALE;
            }
        }
    }

    const float4* thv4 = reinterpret_cast<const float4*>(thc);
    float acc[4] = {0.f, 0.f, 0.f, 0.f};

#pragma unroll
    for (int k = 0; k < 27; ++k) {
        const float4 t4 = thv4[k * 4 + wv];   // wave-uniform b128 broadcast
        const float tho[4] = {t4.x, t4.y, t4.z, t4.w};
#pragma unroll
        for (int i = 0; i < 4; ++i) {
            const float t    = v[k] + tho[i];                     // a*32+256
            const float tc   = fminf(fmaxf(t, 0.f), 1023.0f);     // med3
            const float fl   = floorf(tc);
            const float fr   = tc - fl;
            const int   ii   = (int)fl;
            const float2 cf  = tab[ii];                           // b64 read
            const float fv   = fmaf(cf.y, fr, cf.x);              // lerp
            const float flin = fmaf(t, LIN_A, LIN_B);             // a>24 tail
            acc[i] += (t > 1023.0f) ? flin : fv;
        }
    }

#pragma unroll
    for (int i = 0; i < 4; ++i) {
        const int   c  = cbase + wv * 4 + i;
        const float vo = acc[i] * OUT_SCALE;
        vout[(n << 16) + (c << 10) + hw] = vo;   // NCHW, coalesced per wave

        float s = vo, q = vo * vo;
#pragma unroll
        for (int off = 32; off > 0; off >>= 1) {
            s += __shfl_xor(s, off, 64);
            q += __shfl_xor(q, off, 64);
        }
        if (lane == 0) {
            psum[chunk * 64 + c] = s;
            psq [chunk * 64 + c] = q;
        }
    }
}

// ---------------------------------------------------------------------------
// Kernel 2: reduce 512 partials per channel (double), produce
// scale = gamma * rstd, shift = beta - mean * scale.
// ---------------------------------------------------------------------------
__global__ __launch_bounds__(256)
void nlc_stats(const float* __restrict__ psum, const float* __restrict__ psq,
               const float* __restrict__ gamma, const float* __restrict__ beta,
               float* __restrict__ ss)
{
    __shared__ double ls[256], lq[256];
    const int tid  = threadIdx.x;
    const int c    = tid & 63;
    const int part = tid >> 6;

    double s = 0.0, q = 0.0;
    for (int j = part; j < NCHUNK; j += 4) {
        s += (double)psum[j * 64 + c];
        q += (double)psq [j * 64 + c];
    }
    ls[tid] = s;
    lq[tid] = q;
    __syncthreads();
    if (part == 0) {
        s = ls[c] + ls[c + 64] + ls[c + 128] + ls[c + 192];
        q = lq[c] + lq[c + 64] + lq[c + 128] + lq[c + 192];
        const double inv  = 1.0 / 32768.0;
        const double mean = s * inv;
        const double var  = q * inv - mean * mean;   // biased (ddof=0)
        const float  rstd = (float)(1.0 / sqrt(var + 1e-5));
        const float  sc   = gamma[c] * rstd;
        const float  sh   = beta[c] - (float)mean * sc;
        ss[c]      = sc;
        ss[64 + c] = sh;
    }
}

// ---------------------------------------------------------------------------
// Kernel 3: in-place BN apply on d_out, float4-vectorized.
// ---------------------------------------------------------------------------
__global__ __launch_bounds__(256)
void nlc_apply(float* __restrict__ vout, const float* __restrict__ ss)
{
    const int i = blockIdx.x * 256 + threadIdx.x;      // float4 index
    const int c = (i >> 8) & 63;                       // 256 float4 / channel
    float4 vv = reinterpret_cast<const float4*>(vout)[i];
    const float sc = ss[c];
    const float sh = ss[64 + c];
    vv.x = fmaf(vv.x, sc, sh);
    vv.y = fmaf(vv.y, sc, sh);
    vv.z = fmaf(vv.z, sc, sh);
    vv.w = fmaf(vv.w, sc, sh);
    reinterpret_cast<float4*>(vout)[i] = vv;
}

extern "C" void kernel_launch(void* const* d_in, const int* in_sizes, int n_in,
                              void* d_out, int out_size, void* d_ws, size_t ws_size,
                              hipStream_t stream)
{
    const float* x     = (const float*)d_in[0];
    const float* theta = (const float*)d_in[1];
    const float* gamma = (const float*)d_in[2];
    const float* beta  = (const float*)d_in[3];
    float* out = (float*)d_out;

    float* psum = (float*)d_ws;                 // 512*64 floats
    float* psq  = psum + NCHUNK * 64;           // 512*64 floats
    float* ss   = psq  + NCHUNK * 64;           // 128 floats (scale, shift)

    nlc_compute<<<NCHUNK * 4, 256, 0, stream>>>(x, theta, out, psum, psq);
    nlc_stats  <<<1, 256, 0, stream>>>(psum, psq, gamma, beta, ss);
    nlc_apply  <<<2097152 / 4 / 256, 256, 0, stream>>>(out, ss);
}

// Round 3
// 38.887 us; speedup vs baseline: 3.0890x; 3.0890x over previous
//
#include <hip/hip_runtime.h>

// NonLinearConv2d: unfold(3x3,pad1) -> sum_k f((v_k - theta_kc)/D) with
// f(a) = softplus(a)^2 - softplus(a-DLT)^2, scaled by ALPHA*R_TIA, then
// BatchNorm2d (training, biased stats) per channel.
//
// Round 3: branchless shared-exponential formulation. Both softplus share one
// exp: e^(a-DLT) = e^a * e^-DLT. Per term: 1 v_exp + 2 v_log + ~8 VALU, no
// memory ops, no branches. logs kept in log2 units; final scale absorbs ln2^2.

constexpr float INV_D  = 13.333333333333334f;   // 1/(2*n*VT) = 1/0.075
constexpr float C_NEG  = 0.2635971381157267f;   // e^-(V_D/DENOM) = e^-4/3
// ALPHA * R_TIA * ln(2)^2  (l1,l2 are softplus in log2 units)
constexpr float OUT_SC = 5.625e-5f * 0.4804530139182014f;
constexpr int   NCHUNK = 512;                   // 32768 pixels / 64

// ---------------------------------------------------------------------------
// Kernel 1: V_out (into d_out) + per-(channel,chunk) partial sum / sumsq.
// Grid: 2048 = 512 pixel-chunks x 4 channel-groups; block 256 = 4 waves;
// wave handles 64 consecutive pixels x 4 channels.
// ---------------------------------------------------------------------------
__global__ __launch_bounds__(256, 4)
void nlc_compute(const float* __restrict__ x, const float* __restrict__ theta,
                 float* __restrict__ vout, float* __restrict__ psum,
                 float* __restrict__ psq)
{
    __shared__ alignas(16) float thc[27 * 16];  // -theta*INV_D, block's 16 ch
    const int tid   = threadIdx.x;
    const int chunk = blockIdx.x >> 2;
    const int cbase = (blockIdx.x & 3) * 16;

    for (int i = tid; i < 27 * 16; i += 256) {
        const int k = i >> 4, cc = i & 15;
        thc[i] = -theta[k * 64 + cbase + cc] * INV_D;
    }
    __syncthreads();

    const int lane = tid & 63;
    const int wv   = tid >> 6;
    const int p    = chunk * 64 + lane;   // global pixel id
    const int n    = p >> 10;
    const int hw   = p & 1023;
    const int h    = hw >> 5;
    const int w    = hw & 31;

    // 27 patch values * INV_D (channel-major then ki,kj = unfold order)
    float v[27];
    const float* xn = x + n * 3072;
#pragma unroll
    for (int ci = 0; ci < 3; ++ci) {
#pragma unroll
        for (int ki = 0; ki < 3; ++ki) {
#pragma unroll
            for (int kj = 0; kj < 3; ++kj) {
                const int hh = h + ki - 1;
                const int ww = w + kj - 1;
                float val = 0.f;
                if (hh >= 0 && hh < 32 && ww >= 0 && ww < 32)
                    val = xn[ci * 1024 + hh * 32 + ww];
                v[ci * 9 + ki * 3 + kj] = val * INV_D;
            }
        }
    }

    const float4* thv4 = reinterpret_cast<const float4*>(thc);
    float acc[4] = {0.f, 0.f, 0.f, 0.f};

#pragma unroll
    for (int k = 0; k < 27; ++k) {
        const float4 t4 = thv4[k * 4 + wv];   // wave-uniform b128 broadcast
        const float tho[4] = {t4.x, t4.y, t4.z, t4.w};
#pragma unroll
        for (int i = 0; i < 4; ++i) {
            const float a  = v[k] + tho[i];
            const float E  = __expf(a);                    // e^a (0 if a<<0)
            const float l1 = __log2f(1.0f + E);            // sp(a)*log2e
            const float l2 = __log2f(fmaf(E, C_NEG, 1.0f)); // sp(a-DLT)*log2e
            acc[i] = fmaf(l1 - l2, l1 + l2, acc[i]);
        }
    }

#pragma unroll
    for (int i = 0; i < 4; ++i) {
        const int   c  = cbase + wv * 4 + i;
        const float vo = acc[i] * OUT_SC;
        vout[(n << 16) + (c << 10) + hw] = vo;   // NCHW, coalesced per wave

        float s = vo, q = vo * vo;
#pragma unroll
        for (int off = 32; off > 0; off >>= 1) {
            s += __shfl_xor(s, off, 64);
            q += __shfl_xor(q, off, 64);
        }
        if (lane == 0) {
            psum[c * NCHUNK + chunk] = s;    // [channel][chunk] layout
            psq [c * NCHUNK + chunk] = q;
        }
    }
}

// ---------------------------------------------------------------------------
// Kernel 2: 64 blocks (one per channel); reduce 512 partials (double),
// produce scale = gamma * rstd, shift = beta - mean * scale.
// ---------------------------------------------------------------------------
__global__ __launch_bounds__(256)
void nlc_stats(const float* __restrict__ psum, const float* __restrict__ psq,
               const float* __restrict__ gamma, const float* __restrict__ beta,
               float* __restrict__ ss)
{
    const int c   = blockIdx.x;
    const int tid = threadIdx.x;

    double s = (double)psum[c * NCHUNK + tid] + (double)psum[c * NCHUNK + tid + 256];
    double q = (double)psq [c * NCHUNK + tid] + (double)psq [c * NCHUNK + tid + 256];
#pragma unroll
    for (int off = 32; off > 0; off >>= 1) {
        s += __shfl_xor(s, off, 64);
        q += __shfl_xor(q, off, 64);
    }
    __shared__ double ls[4], lq[4];
    if ((tid & 63) == 0) { ls[tid >> 6] = s; lq[tid >> 6] = q; }
    __syncthreads();
    if (tid == 0) {
        s = ls[0] + ls[1] + ls[2] + ls[3];
        q = lq[0] + lq[1] + lq[2] + lq[3];
        const double inv  = 1.0 / 32768.0;
        const double mean = s * inv;
        const double var  = q * inv - mean * mean;   // biased (ddof=0)
        const float  rstd = (float)(1.0 / sqrt(var + 1e-5));
        const float  sc   = gamma[c] * rstd;
        const float  sh   = beta[c] - (float)mean * sc;
        ss[c]      = sc;
        ss[64 + c] = sh;
    }
}

// ---------------------------------------------------------------------------
// Kernel 3: in-place BN apply on d_out, float4-vectorized.
// ---------------------------------------------------------------------------
__global__ __launch_bounds__(256)
void nlc_apply(float* __restrict__ vout, const float* __restrict__ ss)
{
    const int i = blockIdx.x * 256 + threadIdx.x;      // float4 index
    const int c = (i >> 8) & 63;                       // 256 float4 / channel
    float4 vv = reinterpret_cast<const float4*>(vout)[i];
    const float sc = ss[c];
    const float sh = ss[64 + c];
    vv.x = fmaf(vv.x, sc, sh);
    vv.y = fmaf(vv.y, sc, sh);
    vv.z = fmaf(vv.z, sc, sh);
    vv.w = fmaf(vv.w, sc, sh);
    reinterpret_cast<float4*>(vout)[i] = vv;
}

extern "C" void kernel_launch(void* const* d_in, const int* in_sizes, int n_in,
                              void* d_out, int out_size, void* d_ws, size_t ws_size,
                              hipStream_t stream)
{
    const float* x     = (const float*)d_in[0];
    const float* theta = (const float*)d_in[1];
    const float* gamma = (const float*)d_in[2];
    const float* beta  = (const float*)d_in[3];
    float* out = (float*)d_out;

    float* psum = (float*)d_ws;                 // 64*512 floats
    float* psq  = psum + 64 * NCHUNK;           // 64*512 floats
    float* ss   = psq  + 64 * NCHUNK;           // 128 floats (scale, shift)

    nlc_compute<<<NCHUNK * 4, 256, 0, stream>>>(x, theta, out, psum, psq);
    nlc_stats  <<<64, 256, 0, stream>>>(psum, psq, gamma, beta, ss);
    nlc_apply  <<<2097152 / 4 / 256, 256, 0, stream>>>(out, ss);
}

// Round 4
// 34.998 us; speedup vs baseline: 3.4323x; 1.1111x over previous
//
#include <hip/hip_runtime.h>

// NonLinearConv2d: unfold(3x3,pad1) -> sum_k f((v_k - theta_kc)/D) with
// f(a) = softplus(a)^2 - softplus(a-DLT)^2, then BatchNorm2d (training,
// biased stats) per channel.
//
// Round 4: factor the exponential. e^a = e^{v_k} * e^{-theta_kc/D}; e^{v_k}
// hoisted per pixel (27 exps/thread), e^{-theta/D} staged in LDS. Inner term:
// 2 v_log + 5 VALU, no exp, no branches, no memory ops. OUT_SCALE folded
// into the BN epilogue (d_out pass 1 holds raw log2^2 accumulators).

constexpr float INV_D  = 13.333333333333334f;   // 1/(2*n*VT) = 1/0.075
constexpr float C_NEG  = 0.2635971381157267f;   // e^-(V_D/DENOM) = e^-4/3
// V = acc * OUT_SC;  OUT_SC = ALPHA * R_TIA * ln(2)^2
constexpr double OUT_SC = 5.625e-5 * 0.48045301391820142;
constexpr int   NCHUNK = 512;                   // 32768 pixels / 64

// ---------------------------------------------------------------------------
// Kernel 1: raw acc (into d_out) + per-(channel,chunk) partial sum / sumsq.
// Grid: 2048 = 512 pixel-chunks x 4 channel-groups; block 256 = 4 waves;
// wave handles 64 consecutive pixels x 4 channels.
// ---------------------------------------------------------------------------
__global__ __launch_bounds__(256, 4)
void nlc_compute(const float* __restrict__ x, const float* __restrict__ theta,
                 float* __restrict__ vout, float* __restrict__ psum,
                 float* __restrict__ psq)
{
    __shared__ alignas(16) float thc[27 * 16];  // e^{-theta*INV_D}, 16 ch
    const int tid   = threadIdx.x;
    const int chunk = blockIdx.x >> 2;
    const int cbase = (blockIdx.x & 3) * 16;

    for (int i = tid; i < 27 * 16; i += 256) {
        const int k = i >> 4, cc = i & 15;
        thc[i] = __expf(-theta[k * 64 + cbase + cc] * INV_D);
    }
    __syncthreads();

    const int lane = tid & 63;
    const int wv   = tid >> 6;
    const int p    = chunk * 64 + lane;   // global pixel id
    const int n    = p >> 10;
    const int hw   = p & 1023;
    const int h    = hw >> 5;
    const int w    = hw & 31;

    // e^{v_k * INV_D} for the 27 patch values (channel-major then ki,kj =
    // unfold order); zero-padded borders give e^0 = 1 times eth -> handled
    // exactly (a = -theta/D, correct).
    float Ev[27];
    const float* xn = x + n * 3072;
#pragma unroll
    for (int ci = 0; ci < 3; ++ci) {
#pragma unroll
        for (int ki = 0; ki < 3; ++ki) {
#pragma unroll
            for (int kj = 0; kj < 3; ++kj) {
                const int hh = h + ki - 1;
                const int ww = w + kj - 1;
                float val = 0.f;
                if (hh >= 0 && hh < 32 && ww >= 0 && ww < 32)
                    val = xn[ci * 1024 + hh * 32 + ww];
                Ev[ci * 9 + ki * 3 + kj] =
                    fminf(__expf(val * INV_D), 3.0e38f);
            }
        }
    }

    const float4* thv4 = reinterpret_cast<const float4*>(thc);
    float acc[4] = {0.f, 0.f, 0.f, 0.f};

#pragma unroll
    for (int k = 0; k < 27; ++k) {
        const float4 t4 = thv4[k * 4 + wv];   // wave-uniform b128 broadcast
        const float tho[4] = {t4.x, t4.y, t4.z, t4.w};
#pragma unroll
        for (int i = 0; i < 4; ++i) {
            const float E  = Ev[k] * tho[i];                // e^{(v-th)/D}
            const float q1 = 1.0f + E;
            const float q2 = fmaf(E, C_NEG, 1.0f);
            const float l1 = __log2f(q1);                   // sp(a)*log2e
            const float l2 = __log2f(q2);                   // sp(a-DLT)*log2e
            acc[i] = fmaf(l1, l1, acc[i]);
            acc[i] = fmaf(-l2, l2, acc[i]);
        }
    }

#pragma unroll
    for (int i = 0; i < 4; ++i) {
        const int   c  = cbase + wv * 4 + i;
        const float vo = acc[i];                 // raw (unscaled) accumulator
        vout[(n << 16) + (c << 10) + hw] = vo;   // NCHW, coalesced per wave

        float s = vo, q = vo * vo;
#pragma unroll
        for (int off = 32; off > 0; off >>= 1) {
            s += __shfl_xor(s, off, 64);
            q += __shfl_xor(q, off, 64);
        }
        if (lane == 0) {
            psum[c * NCHUNK + chunk] = s;    // [channel][chunk] layout
            psq [c * NCHUNK + chunk] = q;
        }
    }
}

// ---------------------------------------------------------------------------
// Kernel 2: 64 blocks (one per channel); reduce 512 partials (double).
// acc units -> V units via OUT_SC; scale = gamma*rstd*SC,
// shift = beta - mean_acc*scale.
// ---------------------------------------------------------------------------
__global__ __launch_bounds__(256)
void nlc_stats(const float* __restrict__ psum, const float* __restrict__ psq,
               const float* __restrict__ gamma, const float* __restrict__ beta,
               float* __restrict__ ss)
{
    const int c   = blockIdx.x;
    const int tid = threadIdx.x;

    double s = (double)psum[c * NCHUNK + tid] + (double)psum[c * NCHUNK + tid + 256];
    double q = (double)psq [c * NCHUNK + tid] + (double)psq [c * NCHUNK + tid + 256];
#pragma unroll
    for (int off = 32; off > 0; off >>= 1) {
        s += __shfl_xor(s, off, 64);
        q += __shfl_xor(q, off, 64);
    }
    __shared__ double ls[4], lq[4];
    if ((tid & 63) == 0) { ls[tid >> 6] = s; lq[tid >> 6] = q; }
    __syncthreads();
    if (tid == 0) {
        s = ls[0] + ls[1] + ls[2] + ls[3];
        q = lq[0] + lq[1] + lq[2] + lq[3];
        const double inv    = 1.0 / 32768.0;
        const double mean_a = s * inv;                       // acc units
        const double var_a  = q * inv - mean_a * mean_a;     // biased
        const double var_V  = var_a * OUT_SC * OUT_SC;
        const double rstd   = 1.0 / sqrt(var_V + 1e-5);
        const double sc     = (double)gamma[c] * rstd * OUT_SC;  // per acc
        const double sh     = (double)beta[c] - mean_a * sc;
        ss[c]      = (float)sc;
        ss[64 + c] = (float)sh;
    }
}

// ---------------------------------------------------------------------------
// Kernel 3: in-place BN apply on d_out, float4-vectorized.
// ---------------------------------------------------------------------------
__global__ __launch_bounds__(256)
void nlc_apply(float* __restrict__ vout, const float* __restrict__ ss)
{
    const int i = blockIdx.x * 256 + threadIdx.x;      // float4 index
    const int c = (i >> 8) & 63;                       // 256 float4 / channel
    float4 vv = reinterpret_cast<const float4*>(vout)[i];
    const float sc = ss[c];
    const float sh = ss[64 + c];
    vv.x = fmaf(vv.x, sc, sh);
    vv.y = fmaf(vv.y, sc, sh);
    vv.z = fmaf(vv.z, sc, sh);
    vv.w = fmaf(vv.w, sc, sh);
    reinterpret_cast<float4*>(vout)[i] = vv;
}

extern "C" void kernel_launch(void* const* d_in, const int* in_sizes, int n_in,
                              void* d_out, int out_size, void* d_ws, size_t ws_size,
                              hipStream_t stream)
{
    const float* x     = (const float*)d_in[0];
    const float* theta = (const float*)d_in[1];
    const float* gamma = (const float*)d_in[2];
    const float* beta  = (const float*)d_in[3];
    float* out = (float*)d_out;

    float* psum = (float*)d_ws;                 // 64*512 floats
    float* psq  = psum + 64 * NCHUNK;           // 64*512 floats
    float* ss   = psq  + 64 * NCHUNK;           // 128 floats (scale, shift)

    nlc_compute<<<NCHUNK * 4, 256, 0, stream>>>(x, theta, out, psum, psq);
    nlc_stats  <<<64, 256, 0, stream>>>(psum, psq, gamma, beta, ss);
    nlc_apply  <<<2097152 / 4 / 256, 256, 0, stream>>>(out, ss);
}